// Round 2
// baseline (184.859 us; speedup 1.0000x reference)
//
#include <hip/hip_runtime.h>

// CondMul: out[n] = input[n] @ w[inds[n]] + b[inds[n]]
// N=262144 rows, 1024 experts, in=out=32, fp32.
//
// R2: counting sort with GLOBAL atomic cursors (order within bucket is
// arbitrary -> output identical), trivial 1024-wide scan, and a compute
// kernel register-blocked 4 rows/lane so each LDS w-read amortizes over
// 4 rows (wave-level: 1 ds_read_b128 + 1 global_load_dwordx4 + 16 FMA
// per row). HBM floor ~70 MB => ~11 us.

#define N_ROWS      262144
#define N_CLASSES   1024
#define IN_F        32
#define OUT_F       32
#define HIST_BLOCKS 64
#define ROWS_PER_HB (N_ROWS / HIST_BLOCKS)   // 4096, exact

// ---------------- K1: per-block LDS histogram -> global atomic merge ----------------
__global__ __launch_bounds__(256) void k_hist(const int* __restrict__ inds,
                                              int* __restrict__ cnt) {
    __shared__ int h[N_CLASSES];
    const int tid = threadIdx.x;
    for (int c = tid; c < N_CLASSES; c += 256) h[c] = 0;
    __syncthreads();
    const int base = blockIdx.x * ROWS_PER_HB;
    for (int k = 0; k < ROWS_PER_HB; k += 256)
        atomicAdd(&h[inds[base + k + tid]], 1);
    __syncthreads();
    for (int c = tid; c < N_CLASSES; c += 256) {
        int v = h[c];
        if (v) atomicAdd(&cnt[c], v);
    }
}

// ---------------- K2: 1024-wide exclusive scan (pure LDS), init cursors ----------------
__global__ __launch_bounds__(1024) void k_scan(const int* __restrict__ cnt,
                                               int* __restrict__ cls_off,
                                               int* __restrict__ cursor) {
    __shared__ int s[N_CLASSES];
    const int c = threadIdx.x;
    const int v = cnt[c];
    s[c] = v;
    __syncthreads();
    for (int off = 1; off < N_CLASSES; off <<= 1) {
        int t = (c >= off) ? s[c - off] : 0;
        __syncthreads();
        s[c] += t;
        __syncthreads();
    }
    const int excl = s[c] - v;
    cls_off[c] = excl;
    cursor[c] = excl;
    if (c == N_CLASSES - 1) cls_off[N_CLASSES] = s[c];
}

// ---------------- K3: scatter via global atomic cursors ----------------
__global__ __launch_bounds__(256) void k_scatter(const int* __restrict__ inds,
                                                 int* __restrict__ cursor,
                                                 int* __restrict__ rowids) {
    const int row = blockIdx.x * 256 + threadIdx.x;  // grid covers N exactly
    const int c = inds[row];
    const int pos = atomicAdd(&cursor[c], 1);
    rowids[pos] = row;
}

// ---------------- K4: one block per expert, w in LDS, 4 rows/lane ----------------
// 256 threads: oq = tid&7 (output float4 column), rg = tid>>3 (0..31).
// Each block-iteration covers 128 rows; lane handles rows rg*4..rg*4+3.
// Per lane-iter: 32 ds_read_b128 (w, reused x4 rows), 32 global dwordx4
// (x), 512 FMAs -> wave-level 1 LDS + 1 VMEM + 16 FMA per row.
__global__ __launch_bounds__(256) void k_condmul(const float4* __restrict__ input4,
                                                 const float* __restrict__ w,
                                                 const float* __restrict__ bias,
                                                 const int* __restrict__ rowids,
                                                 const int* __restrict__ cls_off,
                                                 float4* __restrict__ out4) {
    __shared__ float4 wlds4[IN_F * 8];  // [k][oq], 4 KiB
    const int cls = blockIdx.x;
    const int tid = threadIdx.x;

    // stage expert weights: w[cls][k][c] -> wlds4[k*8 + c/4]; 256 x 16 B
    wlds4[tid] = ((const float4*)(w + (size_t)cls * IN_F * OUT_F))[tid];

    const int oq = tid & 7;
    const int rg = tid >> 3;
    const float4 bv = ((const float4*)(bias + (size_t)cls * OUT_F))[oq];
    const int start = cls_off[cls];
    const int count = cls_off[cls + 1] - start;
    __syncthreads();
    if (count == 0) return;

    const int iters = (count + 127) >> 7;
    for (int it = 0; it < iters; ++it) {
        const int rbase = it * 128 + rg * 4;
        int rows[4];
        bool val[4];
#pragma unroll
        for (int r = 0; r < 4; ++r) {
            const int ri = rbase + r;
            val[r] = ri < count;
            rows[r] = rowids[start + (val[r] ? ri : 0)];
        }
        float4 x[4][8];
#pragma unroll
        for (int r = 0; r < 4; ++r)
#pragma unroll
            for (int j = 0; j < 8; ++j)
                x[r][j] = input4[(size_t)rows[r] * 8 + j];

        float4 acc[4] = {bv, bv, bv, bv};
#pragma unroll
        for (int j = 0; j < 8; ++j) {
#pragma unroll
            for (int s = 0; s < 4; ++s) {
                const float4 wk = wlds4[(j * 4 + s) * 8 + oq];
#pragma unroll
                for (int r = 0; r < 4; ++r) {
                    const float xs = (s == 0) ? x[r][j].x
                                   : (s == 1) ? x[r][j].y
                                   : (s == 2) ? x[r][j].z
                                              : x[r][j].w;
                    acc[r].x += xs * wk.x;
                    acc[r].y += xs * wk.y;
                    acc[r].z += xs * wk.z;
                    acc[r].w += xs * wk.w;
                }
            }
        }
#pragma unroll
        for (int r = 0; r < 4; ++r)
            if (val[r]) out4[(size_t)rows[r] * 8 + oq] = acc[r];
    }
}

// ---------------- fallback: direct gather (used only if ws too small) ----------------
__global__ __launch_bounds__(256) void k_naive(const float* __restrict__ input,
                                               const int* __restrict__ inds,
                                               const float* __restrict__ w,
                                               const float* __restrict__ bias,
                                               float* __restrict__ out) {
    const int tid = threadIdx.x;
    const int oq = tid & 7;
    const int rg = tid >> 3;
    const int row = blockIdx.x * 32 + rg;
    if (row >= N_ROWS) return;
    const int c = inds[row];
    const float4* xin = (const float4*)(input + (size_t)row * IN_F);
    const float4* wr = (const float4*)(w + (size_t)c * IN_F * OUT_F);
    float4 acc = ((const float4*)(bias + (size_t)c * OUT_F))[oq];
#pragma unroll
    for (int j = 0; j < 8; ++j) {
        const float4 xv = xin[j];
        const float a0 = xv.x, a1 = xv.y, a2 = xv.z, a3 = xv.w;
        const float4 w0 = wr[(j * 4 + 0) * (OUT_F / 4) + oq];
        const float4 w1 = wr[(j * 4 + 1) * (OUT_F / 4) + oq];
        const float4 w2 = wr[(j * 4 + 2) * (OUT_F / 4) + oq];
        const float4 w3 = wr[(j * 4 + 3) * (OUT_F / 4) + oq];
        acc.x += a0 * w0.x; acc.y += a0 * w0.y; acc.z += a0 * w0.z; acc.w += a0 * w0.w;
        acc.x += a1 * w1.x; acc.y += a1 * w1.y; acc.z += a1 * w1.z; acc.w += a1 * w1.w;
        acc.x += a2 * w2.x; acc.y += a2 * w2.y; acc.z += a2 * w2.z; acc.w += a2 * w2.w;
        acc.x += a3 * w3.x; acc.y += a3 * w3.y; acc.z += a3 * w3.z; acc.w += a3 * w3.w;
    }
    ((float4*)(out + (size_t)row * OUT_F))[oq] = acc;
}

extern "C" void kernel_launch(void* const* d_in, const int* in_sizes, int n_in,
                              void* d_out, int out_size, void* d_ws, size_t ws_size,
                              hipStream_t stream) {
    const float* input = (const float*)d_in[0];  // [N, 32] fp32
    const int*   inds  = (const int*)d_in[1];    // [N] int32
    const float* w     = (const float*)d_in[2];  // [1024, 32, 32] fp32
    const float* bias  = (const float*)d_in[3];  // [1024, 1, 32] fp32
    float* out = (float*)d_out;                  // [N, 32] fp32

    // ws layout (ints): cnt[1024] | cls_off[1025 (+3 pad)] | cursor[1024] | rowids[N]
    int* ws = (int*)d_ws;
    int* cnt     = ws;
    int* cls_off = cnt + N_CLASSES;
    int* cursor  = cls_off + N_CLASSES + 1 + 3;
    int* rowids  = cursor + N_CLASSES;
    const size_t need = (size_t)(N_CLASSES + N_CLASSES + 4 + N_CLASSES + N_ROWS) * sizeof(int);

    if (ws_size >= need) {
        hipMemsetAsync(cnt, 0, N_CLASSES * sizeof(int), stream);
        k_hist<<<HIST_BLOCKS, 256, 0, stream>>>(inds, cnt);
        k_scan<<<1, 1024, 0, stream>>>(cnt, cls_off, cursor);
        k_scatter<<<N_ROWS / 256, 256, 0, stream>>>(inds, cursor, rowids);
        k_condmul<<<N_CLASSES, 256, 0, stream>>>((const float4*)input, w, bias,
                                                 rowids, cls_off, (float4*)out);
    } else {
        k_naive<<<N_ROWS / 32, 256, 0, stream>>>(input, inds, w, bias, out);
    }
}

// Round 3
// 162.764 us; speedup vs baseline: 1.1357x; 1.1357x over previous
//
#include <hip/hip_runtime.h>

// CondMul: out[n] = input[n] @ w[inds[n]] + b[inds[n]]
// N=262144 rows, 1024 experts, in=out=32, fp32.
//
// R3: counting sort with ZERO global atomics (R2 lesson: same-address
// device atomics cost ~500 cyc each, serialized -> 55 us for 256-deep
// counters). Deterministic bc[b][c] start matrix, b-major so every
// access in hist/scan/scatter is coalesced; the class-scan's 64-block
// carry chain runs in registers. Compute kernel: w staged in LDS once
// per expert, 4 rows/lane register blocking, rowid prefetch, 2-way
// bucket split for balance. HBM floor ~70 MB => ~11 us.

#define N_ROWS      262144
#define N_CLASSES   1024
#define IN_F        32
#define OUT_F       32
#define HB          64                 // hist/scatter blocks
#define RPB         (N_ROWS / HB)      // 4096 rows per hist block, exact

// ---------------- K1: per-block LDS histogram -> bc[b][c] ----------------
__global__ __launch_bounds__(256) void k_hist(const int4* __restrict__ inds4,
                                              int* __restrict__ bc) {
    __shared__ int h[N_CLASSES];
    const int tid = threadIdx.x;
    for (int c = tid; c < N_CLASSES; c += 256) h[c] = 0;
    __syncthreads();
    const int base4 = blockIdx.x * (RPB / 4);
#pragma unroll
    for (int k = 0; k < RPB / 4; k += 256) {
        const int4 v = inds4[base4 + k + tid];
        atomicAdd(&h[v.x], 1);
        atomicAdd(&h[v.y], 1);
        atomicAdd(&h[v.z], 1);
        atomicAdd(&h[v.w], 1);
    }
    __syncthreads();
    for (int c = tid; c < N_CLASSES; c += 256)
        bc[blockIdx.x * N_CLASSES + c] = h[c];   // coalesced
}

// ------- K2: one block, 1024 threads. Registers carry the 64-block chain -------
__global__ __launch_bounds__(1024) void k_scan(int* __restrict__ bc,
                                               int* __restrict__ cls_off) {
    __shared__ int s[N_CLASSES];
    const int c = threadIdx.x;
    int v[HB];
#pragma unroll
    for (int b = 0; b < HB; ++b)           // 64 independent coalesced loads
        v[b] = bc[b * N_CLASSES + c];
    int total = 0;
#pragma unroll
    for (int b = 0; b < HB; ++b) total += v[b];
    s[c] = total;
    __syncthreads();
    for (int off = 1; off < N_CLASSES; off <<= 1) {   // Hillis-Steele
        int t = (c >= off) ? s[c - off] : 0;
        __syncthreads();
        s[c] += t;
        __syncthreads();
    }
    const int excl = s[c] - total;
    cls_off[c] = excl;
    if (c == N_CLASSES - 1) cls_off[N_CLASSES] = s[c];
    int run = excl;                        // carry chain in registers
#pragma unroll
    for (int b = 0; b < HB; ++b) {         // 64 coalesced stores
        bc[b * N_CLASSES + c] = run;
        run += v[b];
    }
}

// ---------------- K3: scatter via per-block LDS cursors ----------------
__global__ __launch_bounds__(256) void k_scatter(const int* __restrict__ inds,
                                                 const int* __restrict__ bc,
                                                 int* __restrict__ rowids) {
    __shared__ int cur[N_CLASSES];
    const int tid = threadIdx.x;
    for (int c = tid; c < N_CLASSES; c += 256)
        cur[c] = bc[blockIdx.x * N_CLASSES + c];   // coalesced
    __syncthreads();
    const int base = blockIdx.x * RPB;
#pragma unroll
    for (int k = 0; k < RPB; k += 256) {
        const int row = base + k + tid;
        const int pos = atomicAdd(&cur[inds[row]], 1);  // LDS, ~4-deep
        rowids[pos] = row;
    }
}

// ---------------- K4: 2 blocks per expert, w in LDS, 4 rows/lane ----------------
// 256 threads: oq = tid&7 (output float4 col), rg = tid>>3 (0..31).
// Block-iteration = 128 rows; halves interleave chunks (it += 2).
// Wave-level per row: 1 ds_read_b128 (w, reused x4 rows) + 1 gather
// dwordx4 + 16 FMA. Next chunk's rowids prefetched during compute.
__global__ __launch_bounds__(256) void k_condmul(const float4* __restrict__ input4,
                                                 const float* __restrict__ w,
                                                 const float* __restrict__ bias,
                                                 const int* __restrict__ rowids,
                                                 const int* __restrict__ cls_off,
                                                 float4* __restrict__ out4) {
    __shared__ float4 wlds4[IN_F * 8];     // [k][oq], 4 KiB
    const int cls  = blockIdx.x >> 1;
    const int half = blockIdx.x & 1;
    const int tid  = threadIdx.x;

    wlds4[tid] = ((const float4*)(w + (size_t)cls * (IN_F * OUT_F)))[tid];

    const int oq = tid & 7;
    const int rg = tid >> 3;
    const float4 bv = ((const float4*)(bias + (size_t)cls * OUT_F))[oq];
    const int start = cls_off[cls];
    const int count = cls_off[cls + 1] - start;
    __syncthreads();

    const int iters = (count + 127) >> 7;
    int it = half;
    if (it >= iters) return;

    int rows[4];
    bool val[4];
#pragma unroll
    for (int r = 0; r < 4; ++r) {
        const int ri = it * 128 + rg * 4 + r;
        val[r] = ri < count;
        rows[r] = rowids[start + (val[r] ? ri : 0)];
    }

    while (true) {
        const int nxt = it + 2;
        int nrows[4] = {0, 0, 0, 0};
        bool nval[4] = {false, false, false, false};
        if (nxt < iters) {
#pragma unroll
            for (int r = 0; r < 4; ++r) {   // prefetch next chunk's rowids
                const int ri = nxt * 128 + rg * 4 + r;
                nval[r] = ri < count;
                nrows[r] = rowids[start + (nval[r] ? ri : 0)];
            }
        }

        float4 x[4][8];
#pragma unroll
        for (int r = 0; r < 4; ++r)
#pragma unroll
            for (int j = 0; j < 8; ++j)
                x[r][j] = input4[(size_t)rows[r] * 8 + j];

        float4 acc[4] = {bv, bv, bv, bv};
#pragma unroll
        for (int j = 0; j < 8; ++j) {
#pragma unroll
            for (int s = 0; s < 4; ++s) {
                const float4 wk = wlds4[(j * 4 + s) * 8 + oq];
#pragma unroll
                for (int r = 0; r < 4; ++r) {
                    const float xs = (s == 0) ? x[r][j].x
                                   : (s == 1) ? x[r][j].y
                                   : (s == 2) ? x[r][j].z
                                              : x[r][j].w;
                    acc[r].x += xs * wk.x;
                    acc[r].y += xs * wk.y;
                    acc[r].z += xs * wk.z;
                    acc[r].w += xs * wk.w;
                }
            }
        }
#pragma unroll
        for (int r = 0; r < 4; ++r)
            if (val[r]) out4[(size_t)rows[r] * 8 + oq] = acc[r];

        if (nxt >= iters) break;
        it = nxt;
#pragma unroll
        for (int r = 0; r < 4; ++r) { rows[r] = nrows[r]; val[r] = nval[r]; }
    }
}

// ---------------- fallback: direct gather (used only if ws too small) ----------------
__global__ __launch_bounds__(256) void k_naive(const float* __restrict__ input,
                                               const int* __restrict__ inds,
                                               const float* __restrict__ w,
                                               const float* __restrict__ bias,
                                               float* __restrict__ out) {
    const int tid = threadIdx.x;
    const int oq = tid & 7;
    const int rg = tid >> 3;
    const int row = blockIdx.x * 32 + rg;
    if (row >= N_ROWS) return;
    const int c = inds[row];
    const float4* xin = (const float4*)(input + (size_t)row * IN_F);
    const float4* wr = (const float4*)(w + (size_t)c * IN_F * OUT_F);
    float4 acc = ((const float4*)(bias + (size_t)c * OUT_F))[oq];
#pragma unroll
    for (int j = 0; j < 8; ++j) {
        const float4 xv = xin[j];
        const float a0 = xv.x, a1 = xv.y, a2 = xv.z, a3 = xv.w;
        const float4 w0 = wr[(j * 4 + 0) * 8 + oq];
        const float4 w1 = wr[(j * 4 + 1) * 8 + oq];
        const float4 w2 = wr[(j * 4 + 2) * 8 + oq];
        const float4 w3 = wr[(j * 4 + 3) * 8 + oq];
        acc.x += a0 * w0.x; acc.y += a0 * w0.y; acc.z += a0 * w0.z; acc.w += a0 * w0.w;
        acc.x += a1 * w1.x; acc.y += a1 * w1.y; acc.z += a1 * w1.z; acc.w += a1 * w1.w;
        acc.x += a2 * w2.x; acc.y += a2 * w2.y; acc.z += a2 * w2.z; acc.w += a2 * w2.w;
        acc.x += a3 * w3.x; acc.y += a3 * w3.y; acc.z += a3 * w3.z; acc.w += a3 * w3.w;
    }
    ((float4*)(out + (size_t)row * OUT_F))[oq] = acc;
}

extern "C" void kernel_launch(void* const* d_in, const int* in_sizes, int n_in,
                              void* d_out, int out_size, void* d_ws, size_t ws_size,
                              hipStream_t stream) {
    const float* input = (const float*)d_in[0];  // [N, 32] fp32
    const int*   inds  = (const int*)d_in[1];    // [N] int32
    const float* w     = (const float*)d_in[2];  // [1024, 32, 32] fp32
    const float* bias  = (const float*)d_in[3];  // [1024, 1, 32] fp32
    float* out = (float*)d_out;                  // [N, 32] fp32

    // ws layout (ints): bc[64][1024] | cls_off[1025 (+3 pad)] | rowids[N]
    int* ws = (int*)d_ws;
    int* bc      = ws;
    int* cls_off = bc + HB * N_CLASSES;
    int* rowids  = cls_off + N_CLASSES + 1 + 3;
    const size_t need = (size_t)(HB * N_CLASSES + N_CLASSES + 4 + N_ROWS) * sizeof(int);

    if (ws_size >= need) {
        k_hist<<<HB, 256, 0, stream>>>((const int4*)inds, bc);
        k_scan<<<1, 1024, 0, stream>>>(bc, cls_off);
        k_scatter<<<HB, 256, 0, stream>>>(inds, bc, rowids);
        k_condmul<<<2 * N_CLASSES, 256, 0, stream>>>((const float4*)input, w, bias,
                                                     rowids, cls_off, (float4*)out);
    } else {
        k_naive<<<N_ROWS / 32, 256, 0, stream>>>(input, inds, w, bias, out);
    }
}